// Round 9
// baseline (126.685 us; speedup 1.0000x reference)
//
#include <hip/hip_runtime.h>

// NaiveCollider: uniform-grid broad phase, exact jnp.nonzero ordered-compaction
// semantics. 4 graph nodes: memset(12.5KB) -> fill -> count -> final.
// R8 lesson: ~25k device-scope atomicAdds on out[] cost ~50us (WRITE_SIZE 662KB
// vs 64KB logical = XCD L2 line ping-pong). This round: SYMMETRIC GATHER —
// each body computes its own delta (pairs evaluated from both endpoints, same
// formula acc -= 0.5*sc*(o-me)), one coalesced store, ZERO atomics on out.
// count uses plain seg-strided stores (carry-free packed add in scan).

constexpr int NB = 8192;
constexpr int GRID_DIM = 56;              // cell 2.0 >= max rsum; 112/2
constexpr int NCELLS = GRID_DIM * GRID_DIM;
constexpr int CAP = 20;                   // max bodies/cell (Poisson mean 2.6)
constexpr int NBLK = 96;
constexpr int RPB = (NB + NBLK - 1) / NBLK;  // 86 rows/block
constexpr float INV_CELL = 0.5f;
constexpr float EPS = 1e-12f;
constexpr int INF = 0x7fffffff;

// workspace int offsets
constexpr int O_CCOUNT = 0;                         // 3136
constexpr int O_COMB   = O_CCOUNT + NCELLS;         // 3*NB (12544B off, 16B ok)
constexpr int O_CELLS  = (O_COMB + 3 * NB + 3) & ~3;  // float4[NCELLS*CAP]

__device__ __forceinline__ int cell_of(float v) {
    int c = (int)(v * INV_CELL);
    return c > GRID_DIM - 1 ? GRID_DIM - 1 : (c < 0 ? 0 : c);
}

__device__ __forceinline__ int wave_incl_scan(int v, int lane) {
#pragma unroll
    for (int off = 1; off < 64; off <<= 1) {
        int y = __shfl_up(v, off);
        if (lane >= off) v += y;
    }
    return v;
}

__global__ void fill_kernel(const float2* __restrict__ centers,
                            const float* __restrict__ radii,
                            int* __restrict__ ccount,
                            float4* __restrict__ cells) {
    const int t = blockIdx.x * blockDim.x + threadIdx.x;
    if (t >= NB) return;
    const float2 c = centers[t];
    const int cell = cell_of(c.y) * GRID_DIM + cell_of(c.x);
    const int slot = atomicAdd(&ccount[cell], 1);
    if (slot < CAP)
        cells[cell * CAP + slot] = make_float4(c.x, c.y, radii[t], __int_as_float(t));
}

// 3 threads/body (one per y-row of 3x3 hood); PLAIN store of packed (rc<<8|hc).
__global__ void count_kernel(const float2* __restrict__ centers,
                             const float* __restrict__ radii,
                             const int* __restrict__ ccount,
                             const float4* __restrict__ cells,
                             int* __restrict__ comb) {
    const int t = blockIdx.x * blockDim.x + threadIdx.x;
    if (t >= 3 * NB) return;
    const int i = t & (NB - 1);
    const int seg = t >> 13;
    const float2 ci = centers[i];
    const float ri = radii[i];
    const int cx = cell_of(ci.x), cy = cell_of(ci.y);
    const int yy = cy - 1 + seg;
    int rc = 0, hc = 0;
    if (yy >= 0 && yy < GRID_DIM) {
        const int x0 = max(cx - 1, 0), x1 = min(cx + 1, GRID_DIM - 1);
        for (int xx = x0; xx <= x1; ++xx) {
            const int c = yy * GRID_DIM + xx;
            const int n = min(ccount[c], CAP);
            const float4* p = cells + c * CAP;
            for (int k = 0; k < n; ++k) {
                const float4 o = p[k];
                if (__float_as_int(o.w) <= i) continue;
                const float rs = ri + o.z;
                const float dx = o.x - ci.x, dy = o.y - ci.y;
                if (fabsf(dx) <= rs && fabsf(dy) <= rs) {
                    ++rc;
                    if (rs - sqrtf(dx * dx + dy * dy + EPS) > 0.f) ++hc;
                }
            }
        }
    }
    comb[t] = (rc << 8) | hc;   // comb[seg*NB + i], zero-filled when out of range
}

// brank/hrank of pair (i,j) among row i's candidates with id < j.
// blim==INF: hrank = plain hit count. Else: per-hit nested brank check
// (only needed if a row is BOTH broad- and narrow-bounded; dead here).
__device__ int2 pair_rank(const int* ccount, const float4* cells,
                          float xi, float yi, float ri, int i, int j, int blim) {
    const int cx = cell_of(xi), cy = cell_of(yi);
    const int x0 = max(cx - 1, 0), x1 = min(cx + 1, GRID_DIM - 1);
    const int y0 = max(cy - 1, 0), y1 = min(cy + 1, GRID_DIM - 1);
    int brank = 0, hrank = 0;
    for (int yy = y0; yy <= y1; ++yy)
        for (int xx = x0; xx <= x1; ++xx) {
            const int c = yy * GRID_DIM + xx;
            const int n = min(ccount[c], CAP);
            for (int k = 0; k < n; ++k) {
                const float4 o2 = cells[c * CAP + k];
                const int j2 = __float_as_int(o2.w);
                if (j2 <= i || j2 >= j) continue;
                const float rs2 = ri + o2.z;
                const float dx2 = o2.x - xi, dy2 = o2.y - yi;
                if (!(fabsf(dx2) <= rs2 && fabsf(dy2) <= rs2)) continue;
                ++brank;
                if (rs2 - sqrtf(dx2 * dx2 + dy2 * dy2 + EPS) > 0.f) {
                    if (blim == INF) ++hrank;
                    else {
                        int b2 = 0;  // brank of j2 itself
                        for (int yb = y0; yb <= y1; ++yb)
                            for (int xb = x0; xb <= x1; ++xb) {
                                const int cb2 = yb * GRID_DIM + xb;
                                const int nb2 = min(ccount[cb2], CAP);
                                for (int k2 = 0; k2 < nb2; ++k2) {
                                    const float4 o3 = cells[cb2 * CAP + k2];
                                    const int j3 = __float_as_int(o3.w);
                                    if (j3 <= i || j3 >= j2) continue;
                                    const float rs3 = ri + o3.z;
                                    if (fabsf(o3.x - xi) <= rs3 && fabsf(o3.y - yi) <= rs3)
                                        ++b2;
                                }
                            }
                        if (b2 < blim) ++hrank;
                    }
                }
            }
        }
    return make_int2(brank, hrank);
}

// Serial fallback: hit count of a broad-cap boundary row (dead when total
// broad pairs <= LB, which holds for this input; kept for correctness).
__device__ int slow_boundary_hits(const int* ccount, const float4* cells,
                                  const float2* centers, const float* radii,
                                  int i, int lim) {
    const float2 ci = centers[i];
    const float ri = radii[i];
    const int cx = cell_of(ci.x), cy = cell_of(ci.y);
    const int x0 = max(cx - 1, 0), x1 = min(cx + 1, GRID_DIM - 1);
    const int y0 = max(cy - 1, 0), y1 = min(cy + 1, GRID_DIM - 1);
    int h = 0;
    for (int yy = y0; yy <= y1; ++yy)
        for (int xx = x0; xx <= x1; ++xx) {
            const int c = yy * GRID_DIM + xx;
            const int n = min(ccount[c], CAP);
            for (int k = 0; k < n; ++k) {
                const float4 o = cells[c * CAP + k];
                const int j = __float_as_int(o.w);
                if (j <= i) continue;
                const float rs = ri + o.z, dx = o.x - ci.x, dy = o.y - ci.y;
                if (!(fabsf(dx) <= rs && fabsf(dy) <= rs)) continue;
                if (rs - sqrtf(dx * dx + dy * dy + EPS) <= 0.f) continue;
                const int2 r = pair_rank(ccount, cells, ci.x, ci.y, ri, i, j, INF);
                if (r.x < lim) ++h;  // r.x = brank of (i,j)
            }
        }
    return h;
}

__global__ __launch_bounds__(256) void final_kernel(
        const float2* __restrict__ centers, const float* __restrict__ radii,
        const int* __restrict__ ccount, const float4* __restrict__ cells,
        const int* __restrict__ comb,
        const int* __restrict__ LBp, const int* __restrict__ LNp,
        float2* __restrict__ out) {
    __shared__ unsigned char sh_pol[NB];        // 0=none, 1=all, 2=special
    __shared__ float sh_ax[RPB * 3], sh_ay[RPB * 3];
    __shared__ int wsum[4];
    __shared__ int spec_n, spec_row[2], spec_blim[2], spec_hlim[2];
    const int tid = threadIdx.x, lane = tid & 63, wid = tid >> 6;
    const int LB = *LBp, LN = *LNp;
    if (tid == 0) spec_n = 0;

    // ---- redundant full scan (each block): comb -> per-row policy ----
    int crc[32];   // packed (rc<<8|hc) summed over 3 segs (carry-free, <256 each)
    {
        const int4* c4 = (const int4*)comb;
#pragma unroll
        for (int k = 0; k < 8; ++k) {
            const int4 a = c4[tid * 8 + k];
            const int4 b = c4[2048 + tid * 8 + k];
            const int4 c = c4[4096 + tid * 8 + k];
            crc[4 * k + 0] = a.x + b.x + c.x;
            crc[4 * k + 1] = a.y + b.y + c.y;
            crc[4 * k + 2] = a.z + b.z + c.z;
            crc[4 * k + 3] = a.w + b.w + c.w;
        }
    }
    const int base = tid * 32;
    int rsum = 0;
#pragma unroll
    for (int k = 0; k < 32; ++k) rsum += crc[k] >> 8;
    int incl = wave_incl_scan(rsum, lane);
    if (lane == 63) wsum[wid] = incl;
    __syncthreads();
    if (wid == 0) {
        const int orig = (lane < 4) ? wsum[lane] : 0;
        const int inc = wave_incl_scan(orig, lane);
        if (lane < 4) wsum[lane] = inc - orig;
    }
    __syncthreads();
    const int runb0 = wsum[wid] + incl - rsum;
    // pass B: hit sums (broad-boundary rows via slow path — dead here)
    int runb = runb0, hsum = 0;
    for (int k = 0; k < 32; ++k) {
        const int rc = crc[k] >> 8, hr = crc[k] & 0xff;
        int hc;
        if (runb >= LB) hc = 0;
        else if (runb + rc <= LB) hc = hr;
        else hc = slow_boundary_hits(ccount, cells, centers, radii, base + k,
                                     LB - runb);
        hsum += hc;
        runb += rc;
    }
    __syncthreads();
    incl = wave_incl_scan(hsum, lane);
    if (lane == 63) wsum[wid] = incl;
    __syncthreads();
    if (wid == 0) {
        const int orig = (lane < 4) ? wsum[lane] : 0;
        const int inc = wave_incl_scan(orig, lane);
        if (lane < 4) wsum[lane] = inc - orig;
    }
    __syncthreads();
    int runh = wsum[wid] + incl - hsum;
    // pass C: policy bytes + spec capture
    runb = runb0;
    for (int k = 0; k < 32; ++k) {
        const int i = base + k;
        const int rc = crc[k] >> 8, hr = crc[k] & 0xff;
        int hc;
        if (runb >= LB) hc = 0;
        else if (runb + rc <= LB) hc = hr;
        else hc = slow_boundary_hits(ccount, cells, centers, radii, i, LB - runb);
        unsigned char p = 0;
        if (hc > 0 && runh < LN) {
            const bool bf = (runb + rc <= LB);
            const bool nf = (runh + hc <= LN);
            if (bf && nf) p = 1;
            else {
                p = 2;
                const int n = atomicAdd(&spec_n, 1);
                if (n < 2) {
                    spec_row[n]  = i;
                    spec_blim[n] = bf ? INF : LB - runb;
                    spec_hlim[n] = nf ? INF : LN - runh;
                }
            }
        }
        sh_pol[i] = p;
        runb += rc;
        runh += hc;
    }
    __syncthreads();
    const int ns = min(spec_n, 2);

    // ---- symmetric gather: 3 threads/body over this block's 86-row slice ----
    const int row_lo = blockIdx.x * RPB;
    for (int u = tid; u < RPB * 3; u += 256) {
        const int b = row_lo + u / 3;
        float ax = 0.f, ay = 0.f;
        if (b < NB) {
            const int seg = u - (u / 3) * 3;
            const float2 cb = centers[b];
            const float rb = radii[b];
            const unsigned char pol_b = sh_pol[b];
            const int cx = cell_of(cb.x), cy = cell_of(cb.y);
            const int yy = cy - 1 + seg;
            if (yy >= 0 && yy < GRID_DIM) {
                const int x0 = max(cx - 1, 0), x1 = min(cx + 1, GRID_DIM - 1);
                for (int xx = x0; xx <= x1; ++xx) {
                    const int c = yy * GRID_DIM + xx;
                    const int n = min(ccount[c], CAP);
                    const float4* p = cells + c * CAP;
                    for (int k = 0; k < n; ++k) {
                        const float4 o = p[k];
                        const int id = __float_as_int(o.w);
                        if (id == b) continue;
                        const float rs = rb + o.z;
                        const float dx = o.x - cb.x, dy = o.y - cb.y;
                        if (!(fabsf(dx) <= rs && fabsf(dy) <= rs)) continue;
                        const bool rowside = id > b;
                        const unsigned char pq = rowside ? pol_b : sh_pol[id];
                        if (pq == 0) continue;
                        const float dist = sqrtf(dx * dx + dy * dy + EPS);
                        const float depth = rs - dist;
                        if (depth <= 0.f) continue;
                        bool apply = (pq == 1);
                        if (!apply) {   // special row: exact rank gate
                            const int ii = rowside ? b : id;
                            const int jj = rowside ? id : b;
                            const int sp = (ns > 1 && spec_row[1] == ii) ? 1 : 0;
                            const float xi = rowside ? cb.x : o.x;
                            const float yi = rowside ? cb.y : o.y;
                            const float ri = rowside ? rb : o.z;
                            const int2 r = pair_rank(ccount, cells, xi, yi, ri,
                                                     ii, jj, spec_blim[sp]);
                            apply = (r.x < spec_blim[sp]) && (r.y < spec_hlim[sp]);
                        }
                        if (apply) {
                            const float sc = 0.5f * depth / dist;
                            ax -= sc * dx;
                            ay -= sc * dy;
                        }
                    }
                }
            }
        }
        sh_ax[u] = ax;
        sh_ay[u] = ay;
    }
    __syncthreads();
    if (tid < RPB) {
        const int b = row_lo + tid;
        if (b < NB) {
            const float2 cb = centers[b];
            const float ax = sh_ax[tid * 3] + sh_ax[tid * 3 + 1] + sh_ax[tid * 3 + 2];
            const float ay = sh_ay[tid * 3] + sh_ay[tid * 3 + 1] + sh_ay[tid * 3 + 2];
            out[b] = make_float2(cb.x + ax, cb.y + ay);
        }
    }
}

extern "C" void kernel_launch(void* const* d_in, const int* in_sizes, int n_in,
                              void* d_out, int out_size, void* d_ws, size_t ws_size,
                              hipStream_t stream) {
    const float2* centers = (const float2*)d_in[0];
    const float* radii    = (const float*)d_in[1];
    const int* LBp = (const int*)d_in[2];
    const int* LNp = (const int*)d_in[3];

    int* ws = (int*)d_ws;
    int* ccount = ws + O_CCOUNT;
    int* comb   = ws + O_COMB;
    float4* cells = (float4*)(ws + O_CELLS);

    hipMemsetAsync(ccount, 0, NCELLS * sizeof(int), stream);
    fill_kernel<<<NB / 256, 256, 0, stream>>>(centers, radii, ccount, cells);
    count_kernel<<<3 * NB / 256, 256, 0, stream>>>(centers, radii, ccount,
                                                   cells, comb);
    final_kernel<<<NBLK, 256, 0, stream>>>(centers, radii, ccount, cells, comb,
                                           LBp, LNp, (float2*)d_out);
}

// Round 10
// 122.064 us; speedup vs baseline: 1.0379x; 1.0379x over previous
//
#include <hip/hip_runtime.h>

// NaiveCollider: uniform-grid broad phase, exact jnp.nonzero ordered-compaction
// semantics. 5 slim graph nodes to LOCALIZE the persistent ~60us phase-3 cost
// (R8 atomics theory refuted: WRITE dropped 662->65KB, dur unchanged):
//   memset : zero ccount + chunk sums + spec slots (12.8 KB)
//   fill   : bin bodies into fixed-cap cell table
//   count  : 3 thr/body seg counts -> comb[]; block-reduced chunk sums (rc,hc)
//   pol    : 32 blocks; chunk prefix + block shuffle-scan -> policy byte/row,
//            spec slots for the <=2 truncation-boundary rows
//   gather : symmetric gather (R9), policy bytes from global, no out atomics
// Broad cap (LB=4N) is ~20 sigma inert for this input (E[broad]=24.5k<32768);
// narrow cap (LN=N) cuts mid-row -> spec slot 0. CAP=20 >> Poisson mean 2.6.

constexpr int NB = 8192;
constexpr int GRID_DIM = 56;              // cell 2.0 >= max rsum; 112/2
constexpr int NCELLS = GRID_DIM * GRID_DIM;
constexpr int CAP = 20;
constexpr int NBLK = 96;
constexpr int RPB = (NB + NBLK - 1) / NBLK;  // 86 rows/block (gather)
constexpr float INV_CELL = 0.5f;
constexpr float EPS = 1e-12f;
constexpr int INF = 0x7fffffff;

// workspace int offsets
constexpr int O_CCOUNT = 0;                        // 3136
constexpr int O_CSUM   = O_CCOUNT + NCELLS;        // 32  (chunk hc sums)
constexpr int O_BSUM   = O_CSUM + 32;              // 32  (chunk rc sums)
constexpr int O_SPEC   = O_BSUM + 32;              // 8   (boundary-row records)
constexpr int O_POL    = O_SPEC + 8;               // NB bytes = 2048 ints
constexpr int O_COMB   = O_POL + NB / 4;           // 3*NB
constexpr int O_CELLS  = (O_COMB + 3 * NB + 3) & ~3;  // float4[NCELLS*CAP]
constexpr int MEMSET_INTS = O_SPEC + 8;            // zero [0, 3208)

__device__ __forceinline__ int cell_of(float v) {
    int c = (int)(v * INV_CELL);
    return c > GRID_DIM - 1 ? GRID_DIM - 1 : (c < 0 ? 0 : c);
}

__device__ __forceinline__ int wave_incl_scan(int v, int lane) {
#pragma unroll
    for (int off = 1; off < 64; off <<= 1) {
        int y = __shfl_up(v, off);
        if (lane >= off) v += y;
    }
    return v;
}

__device__ __forceinline__ int wave_reduce(int v) {
#pragma unroll
    for (int off = 32; off > 0; off >>= 1) v += __shfl_down(v, off);
    return v;
}

__global__ void fill_kernel(const float2* __restrict__ centers,
                            const float* __restrict__ radii,
                            int* __restrict__ ccount,
                            float4* __restrict__ cells) {
    const int t = blockIdx.x * blockDim.x + threadIdx.x;
    if (t >= NB) return;
    const float2 c = centers[t];
    const int cell = cell_of(c.y) * GRID_DIM + cell_of(c.x);
    const int slot = atomicAdd(&ccount[cell], 1);
    if (slot < CAP)
        cells[cell * CAP + slot] = make_float4(c.x, c.y, radii[t], __int_as_float(t));
}

// 3 threads/body (one per y-row of 3x3 hood). Block b: seg b/32, rows
// (b%32)*256..+255 -> chunk (b%32). Packed (rc<<8|hc) store + chunk-sum adds.
__global__ __launch_bounds__(256) void count_kernel(
        const float2* __restrict__ centers, const float* __restrict__ radii,
        const int* __restrict__ ccount, const float4* __restrict__ cells,
        int* __restrict__ comb, int* __restrict__ csum, int* __restrict__ bsum) {
    __shared__ int wred[4];
    const int tid = threadIdx.x;
    const int t = blockIdx.x * 256 + tid;
    const int i = t & (NB - 1);
    const int seg = t >> 13;
    const float2 ci = centers[i];
    const float ri = radii[i];
    const int cx = cell_of(ci.x), cy = cell_of(ci.y);
    const int yy = cy - 1 + seg;
    int rc = 0, hc = 0;
    if (yy >= 0 && yy < GRID_DIM) {
        const int x0 = max(cx - 1, 0), x1 = min(cx + 1, GRID_DIM - 1);
        for (int xx = x0; xx <= x1; ++xx) {
            const int c = yy * GRID_DIM + xx;
            const int n = min(ccount[c], CAP);
            const float4* p = cells + c * CAP;
            for (int k = 0; k < n; ++k) {
                const float4 o = p[k];
                if (__float_as_int(o.w) <= i) continue;
                const float rs = ri + o.z;
                const float dx = o.x - ci.x, dy = o.y - ci.y;
                if (fabsf(dx) <= rs && fabsf(dy) <= rs) {
                    ++rc;
                    if (rs - sqrtf(dx * dx + dy * dy + EPS) > 0.f) ++hc;
                }
            }
        }
    }
    comb[t] = (rc << 8) | hc;
    // block-level chunk sums: (rc<<16)|hc packed, then 2 global atomics
    int s = wave_reduce((rc << 16) | hc);
    if ((tid & 63) == 0) wred[tid >> 6] = s;
    __syncthreads();
    if (tid == 0) {
        const int tot = wred[0] + wred[1] + wred[2] + wred[3];
        const int chunk = blockIdx.x & 31;
        atomicAdd(&bsum[chunk], tot >> 16);
        atomicAdd(&csum[chunk], tot & 0xffff);
    }
}

// brank/hrank of pair (i,j) among row i's candidates with id < j.
// blim==INF: hrank = plain hit count (single pass). Else nested (dead here).
__device__ int2 pair_rank(const int* ccount, const float4* cells,
                          float xi, float yi, float ri, int i, int j, int blim) {
    const int cx = cell_of(xi), cy = cell_of(yi);
    const int x0 = max(cx - 1, 0), x1 = min(cx + 1, GRID_DIM - 1);
    const int y0 = max(cy - 1, 0), y1 = min(cy + 1, GRID_DIM - 1);
    int brank = 0, hrank = 0;
    for (int yy = y0; yy <= y1; ++yy)
        for (int xx = x0; xx <= x1; ++xx) {
            const int c = yy * GRID_DIM + xx;
            const int n = min(ccount[c], CAP);
            for (int k = 0; k < n; ++k) {
                const float4 o2 = cells[c * CAP + k];
                const int j2 = __float_as_int(o2.w);
                if (j2 <= i || j2 >= j) continue;
                const float rs2 = ri + o2.z;
                const float dx2 = o2.x - xi, dy2 = o2.y - yi;
                if (!(fabsf(dx2) <= rs2 && fabsf(dy2) <= rs2)) continue;
                ++brank;
                if (rs2 - sqrtf(dx2 * dx2 + dy2 * dy2 + EPS) > 0.f) {
                    if (blim == INF) ++hrank;
                    else {
                        int b2 = 0;
                        for (int yb = y0; yb <= y1; ++yb)
                            for (int xb = x0; xb <= x1; ++xb) {
                                const int cb2 = yb * GRID_DIM + xb;
                                const int nb2 = min(ccount[cb2], CAP);
                                for (int k2 = 0; k2 < nb2; ++k2) {
                                    const float4 o3 = cells[cb2 * CAP + k2];
                                    const int j3 = __float_as_int(o3.w);
                                    if (j3 <= i || j3 >= j2) continue;
                                    const float rs3 = ri + o3.z;
                                    if (fabsf(o3.x - xi) <= rs3 && fabsf(o3.y - yi) <= rs3)
                                        ++b2;
                                }
                            }
                        if (b2 < blim) ++hrank;
                    }
                }
            }
        }
    return make_int2(brank, hrank);
}

// Hit count of a broad-cap boundary row (dead for this input; kept exact).
__device__ int slow_boundary_hits(const int* ccount, const float4* cells,
                                  const float2* centers, const float* radii,
                                  int i, int lim) {
    const float2 ci = centers[i];
    const float ri = radii[i];
    const int cx = cell_of(ci.x), cy = cell_of(ci.y);
    const int x0 = max(cx - 1, 0), x1 = min(cx + 1, GRID_DIM - 1);
    const int y0 = max(cy - 1, 0), y1 = min(cy + 1, GRID_DIM - 1);
    int h = 0;
    for (int yy = y0; yy <= y1; ++yy)
        for (int xx = x0; xx <= x1; ++xx) {
            const int c = yy * GRID_DIM + xx;
            const int n = min(ccount[c], CAP);
            for (int k = 0; k < n; ++k) {
                const float4 o = cells[c * CAP + k];
                const int j = __float_as_int(o.w);
                if (j <= i) continue;
                const float rs = ri + o.z, dx = o.x - ci.x, dy = o.y - ci.y;
                if (!(fabsf(dx) <= rs && fabsf(dy) <= rs)) continue;
                if (rs - sqrtf(dx * dx + dy * dy + EPS) <= 0.f) continue;
                const int2 r = pair_rank(ccount, cells, ci.x, ci.y, ri, i, j, INF);
                if (r.x < lim) ++h;
            }
        }
    return h;
}

// 32 blocks x 256: per-row policy byte via hierarchical scan.
// spec[0..1]: narrow-boundary row (+1 encoded, 0=invalid), hlim.
// spec[2..4]: broad-boundary row (+1), blim, hlim.
__global__ __launch_bounds__(256) void pol_kernel(
        const float2* __restrict__ centers, const float* __restrict__ radii,
        const int* __restrict__ ccount, const float4* __restrict__ cells,
        const int* __restrict__ comb,
        const int* __restrict__ csum, const int* __restrict__ bsum,
        const int* __restrict__ LBp, const int* __restrict__ LNp,
        unsigned char* __restrict__ pol, int* __restrict__ spec) {
    __shared__ int sh_cs[32], sh_bs[32], wsum[4];
    const int tid = threadIdx.x, lane = tid & 63, wid = tid >> 6;
    const int blk = blockIdx.x;
    const int r = blk * 256 + tid;
    if (tid < 32) { sh_cs[tid] = csum[tid]; sh_bs[tid] = bsum[tid]; }
    __syncthreads();
    int hbase = 0, bbase = 0, btotal = 0;
#pragma unroll
    for (int c = 0; c < 32; ++c) {
        btotal += sh_bs[c];
        if (c < blk) { hbase += sh_cs[c]; bbase += sh_bs[c]; }
    }
    const int LB = *LBp, LN = *LNp;
    const int v = comb[r] + comb[NB + r] + comb[2 * NB + r];  // carry-free
    const int rc = v >> 8, hr = v & 0xff;
    // block scan of packed (rc<<16)|hc
    const int pk = (rc << 16) | hr;
    int incl = wave_incl_scan(pk, lane);
    if (lane == 63) wsum[wid] = incl;
    __syncthreads();
    if (wid == 0) {
        const int orig = (lane < 4) ? wsum[lane] : 0;
        const int inc = wave_incl_scan(orig, lane);
        if (lane < 4) wsum[lane] = inc - orig;
    }
    __syncthreads();
    const int excl = wsum[wid] + incl - pk;
    const int bstart = bbase + (excl >> 16);
    int hstart = hbase + (excl & 0xffff);
    // broad-cap correction (dead when btotal<=LB; chunk sums assume raw hc)
    int hc = hr;
    if (btotal > LB) {
        if (bstart >= LB) hc = 0;
        else if (bstart + rc > LB)
            hc = slow_boundary_hits(ccount, cells, centers, radii, r, LB - bstart);
    }
    unsigned char p = 0;
    if (hc > 0 && hstart < LN) {
        const bool bf = (bstart + rc <= LB);
        const bool nf = (hstart + hc <= LN);
        if (bf && nf) p = 1;
        else {
            p = 2;
            if (!bf) {
                spec[2] = r + 1;
                spec[3] = LB - bstart;
                spec[4] = nf ? INF : LN - hstart;
            } else {
                spec[0] = r + 1;
                spec[1] = LN - hstart;
            }
        }
    }
    pol[r] = p;
}

// Symmetric gather: each body accumulates its own delta from both pair
// endpoints (identical formula), one coalesced store, zero out-atomics.
__global__ __launch_bounds__(256) void gather_kernel(
        const float2* __restrict__ centers, const float* __restrict__ radii,
        const int* __restrict__ ccount, const float4* __restrict__ cells,
        const unsigned char* __restrict__ pol, const int* __restrict__ spec,
        float2* __restrict__ out) {
    __shared__ float sh_ax[RPB * 3], sh_ay[RPB * 3];
    __shared__ int sh_spec[5];
    const int tid = threadIdx.x;
    if (tid < 5) sh_spec[tid] = spec[tid];
    __syncthreads();
    const int sp0_row = sh_spec[0] - 1, sp0_hlim = sh_spec[1];
    const int sp1_row = sh_spec[2] - 1, sp1_blim = sh_spec[3], sp1_hlim = sh_spec[4];
    const int row_lo = blockIdx.x * RPB;
    for (int u = tid; u < RPB * 3; u += 256) {
        const int b = row_lo + u / 3;
        float ax = 0.f, ay = 0.f;
        if (b < NB) {
            const int seg = u - (u / 3) * 3;
            const float2 cb = centers[b];
            const float rb = radii[b];
            const unsigned char pol_b = pol[b];
            const int cx = cell_of(cb.x), cy = cell_of(cb.y);
            const int yy = cy - 1 + seg;
            if (yy >= 0 && yy < GRID_DIM) {
                const int x0 = max(cx - 1, 0), x1 = min(cx + 1, GRID_DIM - 1);
                for (int xx = x0; xx <= x1; ++xx) {
                    const int c = yy * GRID_DIM + xx;
                    const int n = min(ccount[c], CAP);
                    const float4* p = cells + c * CAP;
                    for (int k = 0; k < n; ++k) {
                        const float4 o = p[k];
                        const int id = __float_as_int(o.w);
                        if (id == b) continue;
                        const float rs = rb + o.z;
                        const float dx = o.x - cb.x, dy = o.y - cb.y;
                        if (!(fabsf(dx) <= rs && fabsf(dy) <= rs)) continue;
                        const bool rowside = id > b;
                        const unsigned char pq = rowside ? pol_b : pol[id];
                        if (pq == 0) continue;
                        const float dist = sqrtf(dx * dx + dy * dy + EPS);
                        const float depth = rs - dist;
                        if (depth <= 0.f) continue;
                        bool apply = (pq == 1);
                        if (!apply) {
                            const int ii = rowside ? b : id;
                            const int jj = rowside ? id : b;
                            int blim = INF, hlim = 0;
                            if (ii == sp1_row) { blim = sp1_blim; hlim = sp1_hlim; }
                            else if (ii == sp0_row) { hlim = sp0_hlim; }
                            const float xi = rowside ? cb.x : o.x;
                            const float yi = rowside ? cb.y : o.y;
                            const float ri = rowside ? rb : o.z;
                            const int2 rr = pair_rank(ccount, cells, xi, yi, ri,
                                                      ii, jj, blim);
                            apply = (rr.x < blim) && (rr.y < hlim);
                        }
                        if (apply) {
                            const float sc = 0.5f * depth / dist;
                            ax -= sc * dx;
                            ay -= sc * dy;
                        }
                    }
                }
            }
        }
        sh_ax[u] = ax;
        sh_ay[u] = ay;
    }
    __syncthreads();
    if (tid < RPB) {
        const int b = row_lo + tid;
        if (b < NB) {
            const float2 cb = centers[b];
            out[b] = make_float2(cb.x + sh_ax[tid * 3] + sh_ax[tid * 3 + 1] + sh_ax[tid * 3 + 2],
                                 cb.y + sh_ay[tid * 3] + sh_ay[tid * 3 + 1] + sh_ay[tid * 3 + 2]);
        }
    }
}

extern "C" void kernel_launch(void* const* d_in, const int* in_sizes, int n_in,
                              void* d_out, int out_size, void* d_ws, size_t ws_size,
                              hipStream_t stream) {
    const float2* centers = (const float2*)d_in[0];
    const float* radii    = (const float*)d_in[1];
    const int* LBp = (const int*)d_in[2];
    const int* LNp = (const int*)d_in[3];

    int* ws = (int*)d_ws;
    int* ccount = ws + O_CCOUNT;
    int* csum   = ws + O_CSUM;
    int* bsum   = ws + O_BSUM;
    int* spec   = ws + O_SPEC;
    unsigned char* pol = (unsigned char*)(ws + O_POL);
    int* comb   = ws + O_COMB;
    float4* cells = (float4*)(ws + O_CELLS);

    hipMemsetAsync(ws, 0, MEMSET_INTS * sizeof(int), stream);
    fill_kernel<<<NB / 256, 256, 0, stream>>>(centers, radii, ccount, cells);
    count_kernel<<<3 * NB / 256, 256, 0, stream>>>(centers, radii, ccount, cells,
                                                   comb, csum, bsum);
    pol_kernel<<<NB / 256, 256, 0, stream>>>(centers, radii, ccount, cells, comb,
                                             csum, bsum, LBp, LNp, pol, spec);
    gather_kernel<<<NBLK, 256, 0, stream>>>(centers, radii, ccount, cells, pol,
                                            spec, (float2*)d_out);
}

// Round 11
// 103.466 us; speedup vs baseline: 1.2244x; 1.1798x over previous
//
#include <hip/hip_runtime.h>

// NaiveCollider: uniform-grid broad phase, exact jnp.nonzero ordered-compaction
// semantics. 5 graph nodes: memset -> fill -> count -> pol -> gather.
// R10 localization: gather (3 thr/body, 96 blocks = 1.5 waves/CU) = 50us even
// fully L2-warm -> latency-serialization, not traffic. This round: 9 thr/body
// (one hood CELL each), 293 blocks = 4.3 waves/CU, 3x shorter dependent
// chains, body-major blocks (28 bodies x 9 threads) with LDS reduction.

constexpr int NB = 8192;
constexpr int GRID_DIM = 56;              // cell 2.0 >= max rsum; 112/2
constexpr int NCELLS = GRID_DIM * GRID_DIM;
constexpr int CAP = 20;
constexpr int BPB = 28;                   // bodies per block (9 thr each = 252)
constexpr int TPB9 = BPB * 9;
constexpr int NBLK9 = (NB + BPB - 1) / BPB;  // 293
constexpr float INV_CELL = 0.5f;
constexpr float EPS = 1e-12f;
constexpr int INF = 0x7fffffff;

// workspace int offsets
constexpr int O_CCOUNT = 0;                        // 3136
constexpr int O_CSUM   = O_CCOUNT + NCELLS;        // 32  (chunk hc sums)
constexpr int O_BSUM   = O_CSUM + 32;              // 32  (chunk rc sums)
constexpr int O_SPEC   = O_BSUM + 32;              // 8   (boundary-row records)
constexpr int O_POL    = O_SPEC + 8;               // NB bytes = 2048 ints
constexpr int O_COMB   = O_POL + NB / 4;           // NB
constexpr int O_CELLS  = (O_COMB + NB + 3) & ~3;   // float4[NCELLS*CAP] ~1MB
constexpr int MEMSET_INTS = O_SPEC + 8;            // zero ccount+sums+spec

__device__ __forceinline__ int cell_of(float v) {
    int c = (int)(v * INV_CELL);
    return c > GRID_DIM - 1 ? GRID_DIM - 1 : (c < 0 ? 0 : c);
}

__device__ __forceinline__ int wave_incl_scan(int v, int lane) {
#pragma unroll
    for (int off = 1; off < 64; off <<= 1) {
        int y = __shfl_up(v, off);
        if (lane >= off) v += y;
    }
    return v;
}

__global__ void fill_kernel(const float2* __restrict__ centers,
                            const float* __restrict__ radii,
                            int* __restrict__ ccount,
                            float4* __restrict__ cells) {
    const int t = blockIdx.x * blockDim.x + threadIdx.x;
    if (t >= NB) return;
    const float2 c = centers[t];
    const int cell = cell_of(c.y) * GRID_DIM + cell_of(c.x);
    const int slot = atomicAdd(&ccount[cell], 1);
    if (slot < CAP)
        cells[cell * CAP + slot] = make_float4(c.x, c.y, radii[t], __int_as_float(t));
}

// 9 threads/body (one per 3x3 hood cell). Body-major: block covers 28 bodies.
// Lead thread (cellk==0) sums 9 LDS partials -> comb[b] = (rc<<8)|hc; block
// then adds its 28-body totals into per-256-row chunk sums (<=2 atomics).
__global__ __launch_bounds__(256) void count_kernel(
        const float2* __restrict__ centers, const float* __restrict__ radii,
        const int* __restrict__ ccount, const float4* __restrict__ cells,
        int* __restrict__ comb, int* __restrict__ csum, int* __restrict__ bsum) {
    __shared__ int sh_c[256];
    __shared__ int sh_s[BPB];
    const int tid = threadIdx.x;
    const int local = tid / 9, cellk = tid - local * 9;
    const int b = blockIdx.x * BPB + local;
    int rc = 0, hc = 0;
    if (tid < TPB9 && b < NB) {
        const float2 ci = centers[b];
        const float ri = radii[b];
        const int cx = cell_of(ci.x), cy = cell_of(ci.y);
        const int xx = cx - 1 + cellk % 3, yy = cy - 1 + cellk / 3;
        if (xx >= 0 && xx < GRID_DIM && yy >= 0 && yy < GRID_DIM) {
            const int c = yy * GRID_DIM + xx;
            const int n = min(ccount[c], CAP);
            const float4* p = cells + c * CAP;
            for (int k = 0; k < n; ++k) {
                const float4 o = p[k];
                if (__float_as_int(o.w) <= b) continue;
                const float rs = ri + o.z;
                const float dx = o.x - ci.x, dy = o.y - ci.y;
                if (fabsf(dx) <= rs && fabsf(dy) <= rs) {
                    ++rc;
                    if (rs - sqrtf(dx * dx + dy * dy + EPS) > 0.f) ++hc;
                }
            }
        }
    }
    sh_c[tid] = (rc << 8) | hc;
    __syncthreads();
    if (cellk == 0 && tid < TPB9) {
        int s = 0;
#pragma unroll
        for (int k = 0; k < 9; ++k) s += sh_c[tid + k];
        if (b < NB) comb[b] = s;
        sh_s[local] = (b < NB) ? s : 0;
    }
    __syncthreads();
    if (tid == 0) {
        const int chunk0 = (blockIdx.x * BPB) >> 8;
        int sA = 0, sB = 0;
#pragma unroll
        for (int l = 0; l < BPB; ++l) {
            const int v = sh_s[l];
            const int w = (v >> 8 << 16) | (v & 0xff);  // (rc<<16)|hc
            if (((blockIdx.x * BPB + l) >> 8) == chunk0) sA += w; else sB += w;
        }
        atomicAdd(&bsum[chunk0], sA >> 16);
        atomicAdd(&csum[chunk0], sA & 0xffff);
        if (sB) {
            atomicAdd(&bsum[chunk0 + 1], sB >> 16);
            atomicAdd(&csum[chunk0 + 1], sB & 0xffff);
        }
    }
}

// brank/hrank of pair (i,j) among row i's candidates with id < j.
// blim==INF: hrank = plain hit count (single pass). Else nested (dead here).
__device__ int2 pair_rank(const int* ccount, const float4* cells,
                          float xi, float yi, float ri, int i, int j, int blim) {
    const int cx = cell_of(xi), cy = cell_of(yi);
    const int x0 = max(cx - 1, 0), x1 = min(cx + 1, GRID_DIM - 1);
    const int y0 = max(cy - 1, 0), y1 = min(cy + 1, GRID_DIM - 1);
    int brank = 0, hrank = 0;
    for (int yy = y0; yy <= y1; ++yy)
        for (int xx = x0; xx <= x1; ++xx) {
            const int c = yy * GRID_DIM + xx;
            const int n = min(ccount[c], CAP);
            for (int k = 0; k < n; ++k) {
                const float4 o2 = cells[c * CAP + k];
                const int j2 = __float_as_int(o2.w);
                if (j2 <= i || j2 >= j) continue;
                const float rs2 = ri + o2.z;
                const float dx2 = o2.x - xi, dy2 = o2.y - yi;
                if (!(fabsf(dx2) <= rs2 && fabsf(dy2) <= rs2)) continue;
                ++brank;
                if (rs2 - sqrtf(dx2 * dx2 + dy2 * dy2 + EPS) > 0.f) {
                    if (blim == INF) ++hrank;
                    else {
                        int b2 = 0;
                        for (int yb = y0; yb <= y1; ++yb)
                            for (int xb = x0; xb <= x1; ++xb) {
                                const int cb2 = yb * GRID_DIM + xb;
                                const int nb2 = min(ccount[cb2], CAP);
                                for (int k2 = 0; k2 < nb2; ++k2) {
                                    const float4 o3 = cells[cb2 * CAP + k2];
                                    const int j3 = __float_as_int(o3.w);
                                    if (j3 <= i || j3 >= j2) continue;
                                    const float rs3 = ri + o3.z;
                                    if (fabsf(o3.x - xi) <= rs3 && fabsf(o3.y - yi) <= rs3)
                                        ++b2;
                                }
                            }
                        if (b2 < blim) ++hrank;
                    }
                }
            }
        }
    return make_int2(brank, hrank);
}

// Hit count of a broad-cap boundary row (dead for this input; kept exact).
__device__ int slow_boundary_hits(const int* ccount, const float4* cells,
                                  const float2* centers, const float* radii,
                                  int i, int lim) {
    const float2 ci = centers[i];
    const float ri = radii[i];
    const int cx = cell_of(ci.x), cy = cell_of(ci.y);
    const int x0 = max(cx - 1, 0), x1 = min(cx + 1, GRID_DIM - 1);
    const int y0 = max(cy - 1, 0), y1 = min(cy + 1, GRID_DIM - 1);
    int h = 0;
    for (int yy = y0; yy <= y1; ++yy)
        for (int xx = x0; xx <= x1; ++xx) {
            const int c = yy * GRID_DIM + xx;
            const int n = min(ccount[c], CAP);
            for (int k = 0; k < n; ++k) {
                const float4 o = cells[c * CAP + k];
                const int j = __float_as_int(o.w);
                if (j <= i) continue;
                const float rs = ri + o.z, dx = o.x - ci.x, dy = o.y - ci.y;
                if (!(fabsf(dx) <= rs && fabsf(dy) <= rs)) continue;
                if (rs - sqrtf(dx * dx + dy * dy + EPS) <= 0.f) continue;
                const int2 r = pair_rank(ccount, cells, ci.x, ci.y, ri, i, j, INF);
                if (r.x < lim) ++h;
            }
        }
    return h;
}

// 32 blocks x 256: per-row policy byte via hierarchical scan.
// spec[0..1]: narrow-boundary row (+1, 0=invalid), hlim.
// spec[2..4]: broad-boundary row (+1), blim, hlim.
__global__ __launch_bounds__(256) void pol_kernel(
        const float2* __restrict__ centers, const float* __restrict__ radii,
        const int* __restrict__ ccount, const float4* __restrict__ cells,
        const int* __restrict__ comb,
        const int* __restrict__ csum, const int* __restrict__ bsum,
        const int* __restrict__ LBp, const int* __restrict__ LNp,
        unsigned char* __restrict__ pol, int* __restrict__ spec) {
    __shared__ int sh_cs[32], sh_bs[32], wsum[4];
    const int tid = threadIdx.x, lane = tid & 63, wid = tid >> 6;
    const int blk = blockIdx.x;
    const int r = blk * 256 + tid;
    if (tid < 32) { sh_cs[tid] = csum[tid]; sh_bs[tid] = bsum[tid]; }
    __syncthreads();
    int hbase = 0, bbase = 0, btotal = 0;
#pragma unroll
    for (int c = 0; c < 32; ++c) {
        btotal += sh_bs[c];
        if (c < blk) { hbase += sh_cs[c]; bbase += sh_bs[c]; }
    }
    const int LB = *LBp, LN = *LNp;
    const int v = comb[r];
    const int rc = v >> 8, hr = v & 0xff;
    const int pk = (rc << 16) | hr;
    int incl = wave_incl_scan(pk, lane);
    if (lane == 63) wsum[wid] = incl;
    __syncthreads();
    if (wid == 0) {
        const int orig = (lane < 4) ? wsum[lane] : 0;
        const int inc = wave_incl_scan(orig, lane);
        if (lane < 4) wsum[lane] = inc - orig;
    }
    __syncthreads();
    const int excl = wsum[wid] + incl - pk;
    const int bstart = bbase + (excl >> 16);
    const int hstart = hbase + (excl & 0xffff);
    int hc = hr;
    if (btotal > LB) {   // broad cap active (dead for this input)
        if (bstart >= LB) hc = 0;
        else if (bstart + rc > LB)
            hc = slow_boundary_hits(ccount, cells, centers, radii, r, LB - bstart);
    }
    unsigned char p = 0;
    if (hc > 0 && hstart < LN) {
        const bool bf = (bstart + rc <= LB);
        const bool nf = (hstart + hc <= LN);
        if (bf && nf) p = 1;
        else {
            p = 2;
            if (!bf) {
                spec[2] = r + 1;
                spec[3] = LB - bstart;
                spec[4] = nf ? INF : LN - hstart;
            } else {
                spec[0] = r + 1;
                spec[1] = LN - hstart;
            }
        }
    }
    pol[r] = p;
}

// Symmetric gather, 9 threads/body (one hood cell each), LDS reduce, one
// coalesced store per body, zero out-atomics.
__global__ __launch_bounds__(256) void gather_kernel(
        const float2* __restrict__ centers, const float* __restrict__ radii,
        const int* __restrict__ ccount, const float4* __restrict__ cells,
        const unsigned char* __restrict__ pol, const int* __restrict__ spec,
        float2* __restrict__ out) {
    __shared__ float sh_ax[256], sh_ay[256];
    __shared__ int sh_spec[5];
    const int tid = threadIdx.x;
    if (tid < 5) sh_spec[tid] = spec[tid];
    __syncthreads();
    const int sp0_row = sh_spec[0] - 1, sp0_hlim = sh_spec[1];
    const int sp1_row = sh_spec[2] - 1, sp1_blim = sh_spec[3], sp1_hlim = sh_spec[4];
    const int local = tid / 9, cellk = tid - local * 9;
    const int b = blockIdx.x * BPB + local;
    float ax = 0.f, ay = 0.f;
    if (tid < TPB9 && b < NB) {
        const float2 cb = centers[b];
        const float rb = radii[b];
        const unsigned char pol_b = pol[b];
        const int cx = cell_of(cb.x), cy = cell_of(cb.y);
        const int xx = cx - 1 + cellk % 3, yy = cy - 1 + cellk / 3;
        if (xx >= 0 && xx < GRID_DIM && yy >= 0 && yy < GRID_DIM) {
            const int c = yy * GRID_DIM + xx;
            const int n = min(ccount[c], CAP);
            const float4* p = cells + c * CAP;
            for (int k = 0; k < n; ++k) {
                const float4 o = p[k];
                const int id = __float_as_int(o.w);
                if (id == b) continue;
                const float rs = rb + o.z;
                const float dx = o.x - cb.x, dy = o.y - cb.y;
                if (!(fabsf(dx) <= rs && fabsf(dy) <= rs)) continue;
                const bool rowside = id > b;
                const unsigned char pq = rowside ? pol_b : pol[id];
                if (pq == 0) continue;
                const float dist = sqrtf(dx * dx + dy * dy + EPS);
                const float depth = rs - dist;
                if (depth <= 0.f) continue;
                bool apply = (pq == 1);
                if (!apply) {   // special (truncation-boundary) row: exact gate
                    const int ii = rowside ? b : id;
                    const int jj = rowside ? id : b;
                    int blim = INF, hlim = 0;
                    if (ii == sp1_row) { blim = sp1_blim; hlim = sp1_hlim; }
                    else if (ii == sp0_row) { hlim = sp0_hlim; }
                    const float xi = rowside ? cb.x : o.x;
                    const float yi = rowside ? cb.y : o.y;
                    const float ri = rowside ? rb : o.z;
                    const int2 rr = pair_rank(ccount, cells, xi, yi, ri, ii, jj, blim);
                    apply = (rr.x < blim) && (rr.y < hlim);
                }
                if (apply) {
                    const float sc = 0.5f * depth / dist;
                    ax -= sc * dx;
                    ay -= sc * dy;
                }
            }
        }
    }
    sh_ax[tid] = ax;
    sh_ay[tid] = ay;
    __syncthreads();
    if (cellk == 0 && tid < TPB9 && b < NB) {
        float sx = 0.f, sy = 0.f;
#pragma unroll
        for (int k = 0; k < 9; ++k) { sx += sh_ax[tid + k]; sy += sh_ay[tid + k]; }
        const float2 cb = centers[b];
        out[b] = make_float2(cb.x + sx, cb.y + sy);
    }
}

extern "C" void kernel_launch(void* const* d_in, const int* in_sizes, int n_in,
                              void* d_out, int out_size, void* d_ws, size_t ws_size,
                              hipStream_t stream) {
    const float2* centers = (const float2*)d_in[0];
    const float* radii    = (const float*)d_in[1];
    const int* LBp = (const int*)d_in[2];
    const int* LNp = (const int*)d_in[3];

    int* ws = (int*)d_ws;
    int* ccount = ws + O_CCOUNT;
    int* csum   = ws + O_CSUM;
    int* bsum   = ws + O_BSUM;
    int* spec   = ws + O_SPEC;
    unsigned char* pol = (unsigned char*)(ws + O_POL);
    int* comb   = ws + O_COMB;
    float4* cells = (float4*)(ws + O_CELLS);

    hipMemsetAsync(ws, 0, MEMSET_INTS * sizeof(int), stream);
    fill_kernel<<<NB / 256, 256, 0, stream>>>(centers, radii, ccount, cells);
    count_kernel<<<NBLK9, 256, 0, stream>>>(centers, radii, ccount, cells,
                                            comb, csum, bsum);
    pol_kernel<<<NB / 256, 256, 0, stream>>>(centers, radii, ccount, cells, comb,
                                             csum, bsum, LBp, LNp, pol, spec);
    gather_kernel<<<NBLK9, 256, 0, stream>>>(centers, radii, ccount, cells, pol,
                                             spec, (float2*)d_out);
}

// Round 12
// 91.911 us; speedup vs baseline: 1.3783x; 1.1257x over previous
//
#include <hip/hip_runtime.h>

// NaiveCollider: uniform-grid broad phase, exact jnp.nonzero ordered-compaction
// semantics. 5 graph nodes: memset(ccount) -> fill -> count -> scan -> gather.
// R11->R12: (1) pol[] array eliminated — eligibility is monotone in row index,
// so gating = index compare vs spec rows (no scattered per-entry byte loads);
// (2) 18 thr/body (9 hood cells x 2-way entry parity) -> 586 blocks = 9.2
// waves/CU (was 4.3); (3) scan is one 256-thread block emitting only spec[5].
// Harness floor: ~40us d_ws 0xAA re-poison + ~25-30us reset dispatches.

constexpr int NB = 8192;
constexpr int GRID_DIM = 56;              // cell 2.0 >= max rsum; 112/2
constexpr int NCELLS = GRID_DIM * GRID_DIM;
constexpr int CAP = 20;                   // max bodies/cell (Poisson mean 2.6)
constexpr int BPB = 14;                   // bodies/block (18 thr each = 252)
constexpr int TPB18 = BPB * 18;
constexpr int NBLK = (NB + BPB - 1) / BPB;   // 586 blocks
constexpr float INV_CELL = 0.5f;
constexpr float EPS = 1e-12f;
constexpr int INF = 0x7fffffff;

// workspace int offsets
constexpr int O_CCOUNT = 0;                      // 3136 (memset target)
constexpr int O_SPEC   = O_CCOUNT + NCELLS;      // 8 (zeroed inside scan)
constexpr int O_COMB   = O_SPEC + 8;             // 8192; byte off 12576, 16B ok
constexpr int O_CELLS  = (O_COMB + NB + 3) & ~3; // float4[NCELLS*CAP] ~1MB

__device__ __forceinline__ int cell_of(float v) {
    int c = (int)(v * INV_CELL);
    return c > GRID_DIM - 1 ? GRID_DIM - 1 : (c < 0 ? 0 : c);
}

__device__ __forceinline__ int wave_incl_scan(int v, int lane) {
#pragma unroll
    for (int off = 1; off < 64; off <<= 1) {
        int y = __shfl_up(v, off);
        if (lane >= off) v += y;
    }
    return v;
}

__global__ void fill_kernel(const float2* __restrict__ centers,
                            const float* __restrict__ radii,
                            int* __restrict__ ccount,
                            float4* __restrict__ cells) {
    const int t = blockIdx.x * blockDim.x + threadIdx.x;
    if (t >= NB) return;
    const float2 c = centers[t];
    const int cell = cell_of(c.y) * GRID_DIM + cell_of(c.x);
    const int slot = atomicAdd(&ccount[cell], 1);
    if (slot < CAP)
        cells[cell * CAP + slot] = make_float4(c.x, c.y, radii[t], __int_as_float(t));
}

// 18 threads/body: hood cell (sub>>1) + entry parity (sub&1). Lead thread
// sums 18 LDS partials -> comb[b] = (rc<<8)|hc (hc sum < 256, carry-free).
__global__ __launch_bounds__(256) void count_kernel(
        const float2* __restrict__ centers, const float* __restrict__ radii,
        const int* __restrict__ ccount, const float4* __restrict__ cells,
        int* __restrict__ comb) {
    __shared__ int sh_c[256];
    const int tid = threadIdx.x;
    const int local = tid / 18, sub = tid - local * 18;
    const int b = blockIdx.x * BPB + local;
    int rc = 0, hc = 0;
    if (tid < TPB18 && b < NB) {
        const float2 ci = centers[b];
        const float ri = radii[b];
        const int cx = cell_of(ci.x), cy = cell_of(ci.y);
        const int cellk = sub >> 1, par = sub & 1;
        const int xx = cx - 1 + cellk % 3, yy = cy - 1 + cellk / 3;
        if (xx >= 0 && xx < GRID_DIM && yy >= 0 && yy < GRID_DIM) {
            const int c = yy * GRID_DIM + xx;
            const int n = min(ccount[c], CAP);
            const float4* p = cells + c * CAP;
            for (int k = par; k < n; k += 2) {
                const float4 o = p[k];
                if (__float_as_int(o.w) <= b) continue;
                const float rs = ri + o.z;
                const float dx = o.x - ci.x, dy = o.y - ci.y;
                if (fabsf(dx) <= rs && fabsf(dy) <= rs) {
                    ++rc;
                    if (rs - sqrtf(dx * dx + dy * dy + EPS) > 0.f) ++hc;
                }
            }
        }
    }
    sh_c[tid] = (rc << 8) | hc;
    __syncthreads();
    if (sub == 0 && tid < TPB18 && b < NB) {
        int s = 0;
#pragma unroll
        for (int k = 0; k < 18; ++k) s += sh_c[tid + k];
        comb[b] = s;
    }
}

// brank/hrank of pair (i,j) among row i's candidates with id < j.
// blim==INF: hrank = plain hit count (single pass). Else nested (dead here).
__device__ int2 pair_rank(const int* ccount, const float4* cells,
                          float xi, float yi, float ri, int i, int j, int blim) {
    const int cx = cell_of(xi), cy = cell_of(yi);
    const int x0 = max(cx - 1, 0), x1 = min(cx + 1, GRID_DIM - 1);
    const int y0 = max(cy - 1, 0), y1 = min(cy + 1, GRID_DIM - 1);
    int brank = 0, hrank = 0;
    for (int yy = y0; yy <= y1; ++yy)
        for (int xx = x0; xx <= x1; ++xx) {
            const int c = yy * GRID_DIM + xx;
            const int n = min(ccount[c], CAP);
            for (int k = 0; k < n; ++k) {
                const float4 o2 = cells[c * CAP + k];
                const int j2 = __float_as_int(o2.w);
                if (j2 <= i || j2 >= j) continue;
                const float rs2 = ri + o2.z;
                const float dx2 = o2.x - xi, dy2 = o2.y - yi;
                if (!(fabsf(dx2) <= rs2 && fabsf(dy2) <= rs2)) continue;
                ++brank;
                if (rs2 - sqrtf(dx2 * dx2 + dy2 * dy2 + EPS) > 0.f) {
                    if (blim == INF) ++hrank;
                    else {
                        int b2 = 0;
                        for (int yb = y0; yb <= y1; ++yb)
                            for (int xb = x0; xb <= x1; ++xb) {
                                const int cb2 = yb * GRID_DIM + xb;
                                const int nb2 = min(ccount[cb2], CAP);
                                for (int k2 = 0; k2 < nb2; ++k2) {
                                    const float4 o3 = cells[cb2 * CAP + k2];
                                    const int j3 = __float_as_int(o3.w);
                                    if (j3 <= i || j3 >= j2) continue;
                                    const float rs3 = ri + o3.z;
                                    if (fabsf(o3.x - xi) <= rs3 && fabsf(o3.y - yi) <= rs3)
                                        ++b2;
                                }
                            }
                        if (b2 < blim) ++hrank;
                    }
                }
            }
        }
    return make_int2(brank, hrank);
}

// Hit count of a broad-cap boundary row (dead for this input; kept exact).
__device__ int slow_boundary_hits(const int* ccount, const float4* cells,
                                  const float2* centers, const float* radii,
                                  int i, int lim) {
    const float2 ci = centers[i];
    const float ri = radii[i];
    const int cx = cell_of(ci.x), cy = cell_of(ci.y);
    const int x0 = max(cx - 1, 0), x1 = min(cx + 1, GRID_DIM - 1);
    const int y0 = max(cy - 1, 0), y1 = min(cy + 1, GRID_DIM - 1);
    int h = 0;
    for (int yy = y0; yy <= y1; ++yy)
        for (int xx = x0; xx <= x1; ++xx) {
            const int c = yy * GRID_DIM + xx;
            const int n = min(ccount[c], CAP);
            for (int k = 0; k < n; ++k) {
                const float4 o = cells[c * CAP + k];
                const int j = __float_as_int(o.w);
                if (j <= i) continue;
                const float rs = ri + o.z, dx = o.x - ci.x, dy = o.y - ci.y;
                if (!(fabsf(dx) <= rs && fabsf(dy) <= rs)) continue;
                if (rs - sqrtf(dx * dx + dy * dy + EPS) <= 0.f) continue;
                const int2 r = pair_rank(ccount, cells, ci.x, ci.y, ri, i, j, INF);
                if (r.x < lim) ++h;
            }
        }
    return h;
}

// ONE block x 256: full 8192-row double scan from comb; emits spec only.
// spec[0..1]: narrow-boundary row (+1, 0=none), hlim.
// spec[2..4]: broad-boundary row (+1, 0=none), blim, hlim.
__global__ __launch_bounds__(256) void scan_kernel(
        const float2* __restrict__ centers, const float* __restrict__ radii,
        const int* __restrict__ ccount, const float4* __restrict__ cells,
        const int* __restrict__ comb,
        const int* __restrict__ LBp, const int* __restrict__ LNp,
        int* __restrict__ spec) {
    __shared__ int wsum[4];
    __shared__ int sh_btot;
    const int tid = threadIdx.x, lane = tid & 63, wid = tid >> 6;
    if (tid == 0) { spec[0] = 0; spec[2] = 0; }
    int crc[32];
#pragma unroll
    for (int k = 0; k < 8; ++k) {
        const int4 v = ((const int4*)comb)[tid * 8 + k];
        crc[4 * k] = v.x; crc[4 * k + 1] = v.y; crc[4 * k + 2] = v.z; crc[4 * k + 3] = v.w;
    }
    int rsum = 0;
#pragma unroll
    for (int k = 0; k < 32; ++k) rsum += crc[k] >> 8;
    int incl = wave_incl_scan(rsum, lane);
    if (lane == 63) wsum[wid] = incl;
    __syncthreads();
    if (wid == 0) {
        const int orig = (lane < 4) ? wsum[lane] : 0;
        const int inc = wave_incl_scan(orig, lane);
        if (lane < 4) wsum[lane] = inc - orig;
    }
    __syncthreads();
    const int bstart0 = wsum[wid] + incl - rsum;
    if (tid == 255) sh_btot = bstart0 + rsum;
    __syncthreads();
    const int btotal = sh_btot;
    const int LB = *LBp, LN = *LNp;
    // pass B: per-row hit counts (broad-corrected; dead when btotal<=LB)
    int hcv[32];
    int runb = bstart0, hsum = 0;
#pragma unroll
    for (int k = 0; k < 32; ++k) {
        const int rc = crc[k] >> 8, hr = crc[k] & 0xff;
        int hc = hr;
        if (btotal > LB) {
            if (runb >= LB) hc = 0;
            else if (runb + rc > LB)
                hc = slow_boundary_hits(ccount, cells, centers, radii,
                                        tid * 32 + k, LB - runb);
        }
        hcv[k] = hc;
        hsum += hc;
        runb += rc;
    }
    __syncthreads();
    incl = wave_incl_scan(hsum, lane);
    if (lane == 63) wsum[wid] = incl;
    __syncthreads();
    if (wid == 0) {
        const int orig = (lane < 4) ? wsum[lane] : 0;
        const int inc = wave_incl_scan(orig, lane);
        if (lane < 4) wsum[lane] = inc - orig;
    }
    __syncthreads();
    int runh = wsum[wid] + incl - hsum;
    runb = bstart0;
#pragma unroll
    for (int k = 0; k < 32; ++k) {
        const int i = tid * 32 + k;
        const int rc = crc[k] >> 8, hc = hcv[k];
        if (hc > 0 && runh < LN) {
            const bool bf = (runb + rc <= LB);
            const bool nf = (runh + hc <= LN);
            if (!(bf && nf)) {
                if (!bf) {
                    spec[2] = i + 1;
                    spec[3] = LB - runb;
                    spec[4] = nf ? INF : LN - runh;
                } else {
                    spec[0] = i + 1;
                    spec[1] = LN - runh;
                }
            }
        }
        runb += rc;
        runh += hc;
    }
}

// Symmetric gather, 18 threads/body, index-compare gating (no pol loads),
// LDS reduce, one coalesced store per body, zero out-atomics.
__global__ __launch_bounds__(256) void gather_kernel(
        const float2* __restrict__ centers, const float* __restrict__ radii,
        const int* __restrict__ ccount, const float4* __restrict__ cells,
        const int* __restrict__ spec, float2* __restrict__ out) {
    __shared__ float sh_ax[256], sh_ay[256];
    __shared__ int sh_spec[5];
    const int tid = threadIdx.x;
    if (tid < 5) sh_spec[tid] = spec[tid];
    __syncthreads();
    const int sp0 = sh_spec[0] - 1, sp0_hlim = sh_spec[1];
    const int sp1 = sh_spec[2] - 1, sp1_blim = sh_spec[3], sp1_hlim = sh_spec[4];
    // rows < lim1 fully eligible; rows == sp0/sp1 special; rows > lim1 skip.
    const int lim1 = (sp0 >= 0) ? sp0 : ((sp1 >= 0) ? sp1 : NB);
    const int local = tid / 18, sub = tid - local * 18;
    const int b = blockIdx.x * BPB + local;
    float ax = 0.f, ay = 0.f;
    if (tid < TPB18 && b < NB) {
        const float2 cb = centers[b];
        const float rb = radii[b];
        const int cx = cell_of(cb.x), cy = cell_of(cb.y);
        const int cellk = sub >> 1, par = sub & 1;
        const int xx = cx - 1 + cellk % 3, yy = cy - 1 + cellk / 3;
        if (xx >= 0 && xx < GRID_DIM && yy >= 0 && yy < GRID_DIM) {
            const int c = yy * GRID_DIM + xx;
            const int n = min(ccount[c], CAP);
            const float4* p = cells + c * CAP;
            for (int k = par; k < n; k += 2) {
                const float4 o = p[k];
                const int id = __float_as_int(o.w);
                if (id == b) continue;
                const float rs = rb + o.z;
                const float dx = o.x - cb.x, dy = o.y - cb.y;
                if (!(fabsf(dx) <= rs && fabsf(dy) <= rs)) continue;
                const bool rowside = id > b;
                const int ii = rowside ? b : id;
                const bool special = (ii == sp0) | (ii == sp1);
                if (ii >= lim1 && !special) continue;   // beyond caps
                const float dist = sqrtf(dx * dx + dy * dy + EPS);
                const float depth = rs - dist;
                if (depth <= 0.f) continue;
                bool apply = !special;
                if (special) {   // truncation-boundary row: exact rank gate
                    const int jj = rowside ? id : b;
                    const int blim = (ii == sp1) ? sp1_blim : INF;
                    const int hlim = (ii == sp1) ? sp1_hlim : sp0_hlim;
                    const float xi = rowside ? cb.x : o.x;
                    const float yi = rowside ? cb.y : o.y;
                    const float ri = rowside ? rb : o.z;
                    const int2 rr = pair_rank(ccount, cells, xi, yi, ri, ii, jj, blim);
                    apply = (rr.x < blim) && (rr.y < hlim);
                }
                if (apply) {
                    const float sc = 0.5f * depth / dist;
                    ax -= sc * dx;
                    ay -= sc * dy;
                }
            }
        }
    }
    sh_ax[tid] = ax;
    sh_ay[tid] = ay;
    __syncthreads();
    if (sub == 0 && tid < TPB18 && b < NB) {
        float sx = 0.f, sy = 0.f;
#pragma unroll
        for (int k = 0; k < 18; ++k) { sx += sh_ax[tid + k]; sy += sh_ay[tid + k]; }
        const float2 cb = centers[b];
        out[b] = make_float2(cb.x + sx, cb.y + sy);
    }
}

extern "C" void kernel_launch(void* const* d_in, const int* in_sizes, int n_in,
                              void* d_out, int out_size, void* d_ws, size_t ws_size,
                              hipStream_t stream) {
    const float2* centers = (const float2*)d_in[0];
    const float* radii    = (const float*)d_in[1];
    const int* LBp = (const int*)d_in[2];
    const int* LNp = (const int*)d_in[3];

    int* ws = (int*)d_ws;
    int* ccount = ws + O_CCOUNT;
    int* spec   = ws + O_SPEC;
    int* comb   = ws + O_COMB;
    float4* cells = (float4*)(ws + O_CELLS);

    hipMemsetAsync(ccount, 0, NCELLS * sizeof(int), stream);
    fill_kernel<<<NB / 256, 256, 0, stream>>>(centers, radii, ccount, cells);
    count_kernel<<<NBLK, 256, 0, stream>>>(centers, radii, ccount, cells, comb);
    scan_kernel<<<1, 256, 0, stream>>>(centers, radii, ccount, cells, comb,
                                       LBp, LNp, spec);
    gather_kernel<<<NBLK, 256, 0, stream>>>(centers, radii, ccount, cells,
                                            spec, (float2*)d_out);
}